// Round 1
// baseline (80844.501 us; speedup 1.0000x reference)
//
#include <hip/hip_runtime.h>
#include <math.h>

#define BB 4
#define DDEPTH 31

// ---------------- prep kernels ----------------

// src: [I][O][27] -> dst: [O][I][27] with taps reversed (deconv weight transform)
__global__ void flipw(const float* __restrict__ src, float* __restrict__ dst, int I, int O) {
    int idx = blockIdx.x * blockDim.x + threadIdx.x;
    int total = I * O * 27;
    if (idx >= total) return;
    int t = idx % 27;
    int i = (idx / 27) % I;
    int o = idx / (27 * I);
    dst[idx] = src[((size_t)i * O + o) * 27 + (26 - t)];
}

// bn: [4][C] stacked gamma, beta, mean, var -> scale/shift
__global__ void bnprep(const float* __restrict__ bn, int C,
                       float* __restrict__ sc, float* __restrict__ sh) {
    int c = blockIdx.x * blockDim.x + threadIdx.x;
    if (c >= C) return;
    float g = bn[c], b = bn[C + c], m = bn[2 * C + c], v = bn[3 * C + c];
    float s = g * rsqrtf(v + 1e-5f);
    sc[c] = s;
    sh[c] = b - m * s;
}

// ---------------- conv + bn + activation ----------------
// out[b,co,d,h,w] = act( bn( sum_{ci,kd,kh,kw} in(b,ci,d+kd-1,h+kh-1,w+kw-1) * wt[co,ci,kd,kh,kw] ) )
// in(b,ci,dz,hz,wz) = in0[...hz>>up, wz>>up...] (+ in1[same] if in1 != null)
// act: co < hidden ? tanh : sigmoid
__global__ __launch_bounds__(256) void conv_bn_act(
    const float* __restrict__ in0, const float* __restrict__ in1,
    const float* __restrict__ wt, const float* __restrict__ bnsc,
    const float* __restrict__ bnsh, float* __restrict__ gout,
    int Cin, int Cout, int H, int W, int hidden, int up) {
    __shared__ float sw[64 * 27];

    const int w = threadIdx.x;
    const int h = blockIdx.x * blockDim.y + threadIdx.y;
    const int d = blockIdx.y;
    const int bco = blockIdx.z;
    const int b = bco / Cout;
    const int co = bco % Cout;

    const int nw = Cin * 27;
    for (int i = threadIdx.y * blockDim.x + threadIdx.x; i < nw; i += blockDim.x * blockDim.y)
        sw[i] = wt[(size_t)co * nw + i];
    __syncthreads();

    const int inH = up ? (H >> 1) : H;
    const int inW = up ? (W >> 1) : W;
    const int inHW = inH * inW;
    const size_t inDHW = (size_t)DDEPTH * inHW;

    float acc = 0.f;
    for (int ci = 0; ci < Cin; ++ci) {
        const float* ib = in0 + ((size_t)b * Cin + ci) * inDHW;
        const float* jb = in1 ? in1 + ((size_t)b * Cin + ci) * inDHW : nullptr;
        const float* swc = sw + ci * 27;
#pragma unroll
        for (int kd = 0; kd < 3; ++kd) {
            const int dz = d + kd - 1;
            if ((unsigned)dz >= (unsigned)DDEPTH) continue;
            const float* ibd = ib + (size_t)dz * inHW;
            const float* jbd = jb ? jb + (size_t)dz * inHW : nullptr;
#pragma unroll
            for (int kh = 0; kh < 3; ++kh) {
                const int hz = h + kh - 1;
                if ((unsigned)hz >= (unsigned)H) continue;
                const int hs = up ? (hz >> 1) : hz;
                const float* row = ibd + (size_t)hs * inW;
                const float* row1 = jbd ? jbd + (size_t)hs * inW : nullptr;
                const float* swk = swc + kd * 9 + kh * 3;
#pragma unroll
                for (int kw = 0; kw < 3; ++kw) {
                    const int wz = w + kw - 1;
                    if ((unsigned)wz >= (unsigned)W) continue;
                    const int wsrc = up ? (wz >> 1) : wz;
                    float v = row[wsrc];
                    if (row1) v += row1[wsrc];
                    acc = fmaf(v, swk[kw], acc);
                }
            }
        }
    }

    float y = acc * bnsc[co] + bnsh[co];
    float r;
    if (co < hidden) {
        r = tanhf(y);
    } else {
        r = 1.f / (1.f + __expf(-y));
    }
    if (h < H)
        gout[(((size_t)b * Cout + co) * DDEPTH + d) * ((size_t)H * W) + (size_t)h * W + w] = r;
}

// ---------------- qrnn scan over D ----------------
// g layout: [B][2*hidden][D][HW]; z = ch c, f = ch c+hidden
// h_d = f_d*h_prev + (1-f_d)*z_d  (prev = d-1 fwd, d+1 rev)
__global__ __launch_bounds__(256) void qrnn_scan(
    const float* __restrict__ g, float* __restrict__ out,
    int hidden, int HW, int rev) {
    int idx = blockIdx.x * blockDim.x + threadIdx.x;
    int total = BB * hidden * HW;
    if (idx >= total) return;
    int hw = idx % HW;
    int c = (idx / HW) % hidden;
    int b = idx / (HW * hidden);

    const size_t zb = (((size_t)b * 2 * hidden + c) * DDEPTH) * HW + hw;
    const size_t fb = (((size_t)b * 2 * hidden + c + hidden) * DDEPTH) * HW + hw;
    const size_t ob = (((size_t)b * hidden + c) * DDEPTH) * HW + hw;

    float hc = 0.f;
    for (int t = 0; t < DDEPTH; ++t) {
        int d = rev ? (DDEPTH - 1 - t) : t;
        float z = g[zb + (size_t)d * HW];
        float f = g[fb + (size_t)d * HW];
        hc = f * hc + (1.f - f) * z;
        out[ob + (size_t)d * HW] = hc;
    }
}

extern "C" void kernel_launch(void* const* d_in, const int* in_sizes, int n_in,
                              void* d_out, int out_size, void* d_ws, size_t ws_size,
                              hipStream_t stream) {
    const float* x   = (const float*)d_in[0];
    const float* xs0 = (const float*)d_in[1];
    const float* xs1 = (const float*)d_in[2];
    const float* xs2 = (const float*)d_in[3];
    const float* w0  = (const float*)d_in[4];
    const float* w1  = (const float*)d_in[5];
    const float* w2  = (const float*)d_in[6];
    const float* w3  = (const float*)d_in[7];
    const float* bn0 = (const float*)d_in[8];
    const float* bn1 = (const float*)d_in[9];
    const float* bn2 = (const float*)d_in[10];
    const float* bn3 = (const float*)d_in[11];
    float* out = (float*)d_out;

    // workspace layout (floats)
    float* bufG = (float*)d_ws;             // 65,011,712 floats (260 MB) conv outputs
    float* bufH = bufG + 65011712;          // 32,505,856 floats (130 MB) scan outputs
    float* wc1  = bufH + 32505856;          // 64*32*27
    float* wc3  = wc1 + 55296;              // 32*16*27
    float* bnp  = wc3 + 13824;              // 4 layers x 128 (scale|shift)

    float* sc0 = bnp + 0 * 128;  float* sh0 = sc0 + 64;
    float* sc1 = bnp + 1 * 128;  float* sh1 = sc1 + 64;
    float* sc2 = bnp + 2 * 128;  float* sh2 = sc2 + 64;
    float* sc3 = bnp + 3 * 128;  float* sh3 = sc3 + 64;

    // prep
    flipw<<<(55296 + 255) / 256, 256, 0, stream>>>(w1, wc1, 32, 64);
    flipw<<<(13824 + 255) / 256, 256, 0, stream>>>(w3, wc3, 16, 32);
    bnprep<<<1, 64, 0, stream>>>(bn0, 64, sc0, sh0);
    bnprep<<<1, 64, 0, stream>>>(bn1, 64, sc1, sh1);
    bnprep<<<1, 64, 0, stream>>>(bn2, 32, sc2, sh2);
    bnprep<<<1, 64, 0, stream>>>(bn3, 32, sc3, sh3);

    // ---- layer 1: upsample(x) -> conv(w0) 64->64 @64x64, hidden 32, fwd ----
    {
        dim3 blk(64, 4), grd(64 / 4, DDEPTH, BB * 64);
        conv_bn_act<<<grd, blk, 0, stream>>>(x, nullptr, w0, sc0, sh0, bufG,
                                             64, 64, 64, 64, 32, 1);
        int total = BB * 32 * 64 * 64;
        qrnn_scan<<<(total + 255) / 256, 256, 0, stream>>>(bufG, bufH, 32, 64 * 64, 0);
    }
    // ---- layer 2: (h1+xs2) -> deconv(w1) 32->64 @64x64, hidden 32, rev ----
    {
        dim3 blk(64, 4), grd(64 / 4, DDEPTH, BB * 64);
        conv_bn_act<<<grd, blk, 0, stream>>>(bufH, xs2, wc1, sc1, sh1, bufG,
                                             32, 64, 64, 64, 32, 0);
        int total = BB * 32 * 64 * 64;
        qrnn_scan<<<(total + 255) / 256, 256, 0, stream>>>(bufG, bufH, 32, 64 * 64, 1);
    }
    // ---- layer 3: upsample(h2+xs1) -> conv(w2) 32->32 @128x128, hidden 16, fwd ----
    {
        dim3 blk(128, 2), grd(128 / 2, DDEPTH, BB * 32);
        conv_bn_act<<<grd, blk, 0, stream>>>(bufH, xs1, w2, sc2, sh2, bufG,
                                             32, 32, 128, 128, 16, 1);
        int total = BB * 16 * 128 * 128;
        qrnn_scan<<<(total + 255) / 256, 256, 0, stream>>>(bufG, bufH, 16, 128 * 128, 0);
    }
    // ---- layer 4: (h3+xs0) -> deconv(w3) 16->32 @128x128, hidden 16, rev ----
    {
        dim3 blk(128, 2), grd(128 / 2, DDEPTH, BB * 32);
        conv_bn_act<<<grd, blk, 0, stream>>>(bufH, xs0, wc3, sc3, sh3, bufG,
                                             16, 32, 128, 128, 16, 0);
        int total = BB * 16 * 128 * 128;
        qrnn_scan<<<(total + 255) / 256, 256, 0, stream>>>(bufG, out, 16, 128 * 128, 1);
    }
}

// Round 2
// 4222.806 us; speedup vs baseline: 19.1447x; 19.1447x over previous
//
#include <hip/hip_runtime.h>
#include <math.h>

#define BB 4
#define DD 31

// ---------------- prep kernels ----------------

// shift = beta - mean*scale  (scale folded into weights by wprep)
__global__ void bnprep(const float* __restrict__ bn, int C, float* __restrict__ sh) {
    int c = threadIdx.x;
    if (c >= C) return;
    float g = bn[c], b = bn[C + c], m = bn[2 * C + c], v = bn[3 * C + c];
    float s = g * rsqrtf(v + 1e-5f);
    sh[c] = b - m * s;
}

// dst[ci][t][co] = eff_weight[co][ci][t] * bnscale[co]
// tr=0 (conv):   eff = src[co][ci][t]          (src strides [COUT][CIN][27])
// tr=1 (deconv): eff = src[ci][co][26-t]       (src strides [CIN][COUT][27])
__global__ void wprep(const float* __restrict__ src, const float* __restrict__ bn,
                      float* __restrict__ dst, int CIN, int COUT, int tr) {
    int idx = blockIdx.x * 256 + threadIdx.x;
    int total = CIN * 27 * COUT;
    if (idx >= total) return;
    int co = idx % COUT;
    int t = (idx / COUT) % 27;
    int ci = idx / (COUT * 27);
    float v = tr ? src[((size_t)ci * COUT + co) * 27 + (26 - t)]
                 : src[((size_t)co * CIN + ci) * 27 + t];
    float g = bn[co], var = bn[3 * COUT + co];
    dst[idx] = v * (g * rsqrtf(var + 1e-5f));
}

// ---------------- tiled conv + bn + act ----------------
// Block: 32(w) x HT(h) output tile, ALL COUT channels, one (b,d).
// Thread: 4(w) x 8(co) register accumulator tile.
// Loop ci: stage input patch (input resolution, halo, zero-padded) + 27xCOUT
// weights into LDS, then 27-tap FMA sweep.
template <int CIN, int COUT, int S, int UP, int IN1>
__global__ __launch_bounds__(256) void conv_tile(
    const float* __restrict__ in0, const float* __restrict__ in1,
    const float* __restrict__ wp, const float* __restrict__ bnsh,
    float* __restrict__ gout) {

    constexpr int HT = (COUT == 64) ? 4 : 8;     // 256 thr = 8(wl) * (COUT/8)(cl) * HT(hl)
    constexpr int CL = COUT / 8;
    constexpr int LOG2CL = (CL == 8) ? 3 : 2;
    constexpr int IHT = UP ? (HT / 2 + 2) : (HT + 2);
    constexpr int IWT = UP ? 18 : 34;
    constexpr int NIV = UP ? 4 : 6;
    constexpr int inS = UP ? (S / 2) : S;

    __shared__ float lin[3 * IHT * IWT];
    __shared__ float lw[27 * COUT];

    const int tid = threadIdx.x;
    const int wl = tid & 7;
    const int cl = (tid >> 3) & (CL - 1);
    const int hl = tid >> (3 + LOG2CL);

    const int w0 = blockIdx.x * 32;
    const int h0 = blockIdx.y * HT;
    const int bz = blockIdx.z;
    const int d = bz % DD;
    const int b = bz / DD;

    const int ibh = (h0 - 1) >> UP;   // arithmetic shift: floor((h0-1)/2) for UP
    const int ibw = (w0 - 1) >> UP;
    const int w0t = w0 + wl * 4;
    const int ivbase = UP ? wl * 2 : wl * 4;

    float acc[4][8];
#pragma unroll
    for (int j = 0; j < 4; ++j)
#pragma unroll
        for (int n = 0; n < 8; ++n) acc[j][n] = 0.f;

    const size_t inCstride = (size_t)DD * inS * inS;

    for (int ci = 0; ci < CIN; ++ci) {
        __syncthreads();  // protect LDS from previous iteration's readers
        // ---- stage input patch (zero-padded) ----
        const float* ib = in0 + ((size_t)b * CIN + ci) * inCstride;
        const float* jb = IN1 ? in1 + ((size_t)b * CIN + ci) * inCstride : nullptr;
        for (int idx = tid; idx < 3 * IHT * IWT; idx += 256) {
            int kd = idx / (IHT * IWT);
            int r = idx - kd * (IHT * IWT);
            int ih = r / IWT, iw = r - ih * IWT;
            int dz = d + kd - 1, gh = ibh + ih, gw = ibw + iw;
            float v = 0.f;
            if ((unsigned)dz < (unsigned)DD && (unsigned)gh < (unsigned)inS &&
                (unsigned)gw < (unsigned)inS) {
                size_t o = ((size_t)dz * inS + gh) * inS + gw;
                v = ib[o];
                if (IN1) v += jb[o];
            }
            lin[idx] = v;
        }
        // ---- stage weights for this ci ----
        const float* wsrc = wp + (size_t)ci * 27 * COUT;
        for (int idx = tid; idx < 27 * COUT; idx += 256) lw[idx] = wsrc[idx];
        __syncthreads();

        // ---- 27-tap register-tiled FMA sweep ----
#pragma unroll
        for (int kd = 0; kd < 3; ++kd) {
#pragma unroll
            for (int kh = 0; kh < 3; ++kh) {
                int hz = h0 + hl + kh - 1;
                int ihz = (hz >> UP) - ibh;
                const float* row = lin + (kd * IHT + ihz) * IWT + ivbase;
                float iv[NIV];
#pragma unroll
                for (int i = 0; i < NIV; ++i) iv[i] = row[i];
#pragma unroll
                for (int kw = 0; kw < 3; ++kw) {
                    const float4* wq =
                        (const float4*)(lw + ((kd * 3 + kh) * 3 + kw) * COUT + cl * 8);
                    float4 wa = wq[0], wb = wq[1];
                    float wv[8] = {wa.x, wa.y, wa.z, wa.w, wb.x, wb.y, wb.z, wb.w};
#pragma unroll
                    for (int j = 0; j < 4; ++j) {
                        float v = iv[UP ? ((j + kw + 1) >> 1) : (j + kw)];
#pragma unroll
                        for (int n = 0; n < 8; ++n) acc[j][n] = fmaf(v, wv[n], acc[j][n]);
                    }
                }
            }
        }
    }

    // ---- epilogue: +shift, activation, float4 store ----
    constexpr int hidden = COUT / 2;
#pragma unroll
    for (int n = 0; n < 8; ++n) {
        int co = cl * 8 + n;
        float sh = bnsh[co];
        float4 o;
        float* po = (float*)&o;
#pragma unroll
        for (int j = 0; j < 4; ++j) {
            float y = acc[j][n] + sh;
            po[j] = (co < hidden) ? tanhf(y) : 1.f / (1.f + __expf(-y));
        }
        float4* dst = (float4*)(gout + (((size_t)b * COUT + co) * DD + d) * ((size_t)S * S) +
                                (size_t)(h0 + hl) * S + w0t);
        *dst = o;
    }
}

// ---------------- qrnn scan over D ----------------
__global__ __launch_bounds__(256) void qrnn_scan(
    const float* __restrict__ g, float* __restrict__ out,
    int hidden, int HW, int rev) {
    int idx = blockIdx.x * blockDim.x + threadIdx.x;
    int total = BB * hidden * HW;
    if (idx >= total) return;
    int hw = idx % HW;
    int c = (idx / HW) % hidden;
    int b = idx / (HW * hidden);

    const size_t zb = (((size_t)b * 2 * hidden + c) * DD) * HW + hw;
    const size_t fb = (((size_t)b * 2 * hidden + c + hidden) * DD) * HW + hw;
    const size_t ob = (((size_t)b * hidden + c) * DD) * HW + hw;

    float hc = 0.f;
    for (int t = 0; t < DD; ++t) {
        int d = rev ? (DD - 1 - t) : t;
        float z = g[zb + (size_t)d * HW];
        float f = g[fb + (size_t)d * HW];
        hc = f * hc + (1.f - f) * z;
        out[ob + (size_t)d * HW] = hc;
    }
}

extern "C" void kernel_launch(void* const* d_in, const int* in_sizes, int n_in,
                              void* d_out, int out_size, void* d_ws, size_t ws_size,
                              hipStream_t stream) {
    const float* x   = (const float*)d_in[0];
    const float* xs0 = (const float*)d_in[1];
    const float* xs1 = (const float*)d_in[2];
    const float* xs2 = (const float*)d_in[3];
    const float* w0  = (const float*)d_in[4];
    const float* w1  = (const float*)d_in[5];
    const float* w2  = (const float*)d_in[6];
    const float* w3  = (const float*)d_in[7];
    const float* bn0 = (const float*)d_in[8];
    const float* bn1 = (const float*)d_in[9];
    const float* bn2 = (const float*)d_in[10];
    const float* bn3 = (const float*)d_in[11];
    float* out = (float*)d_out;

    // workspace layout (floats)
    float* bufG = (float*)d_ws;            // 65,011,712
    float* bufH = bufG + 65011712;         // 32,505,856
    float* wp0  = bufH + 32505856;         // 64*27*64 = 110592
    float* wp1  = wp0 + 110592;            // 32*27*64 = 55296
    float* wp2  = wp1 + 55296;             // 32*27*32 = 27648
    float* wp3  = wp2 + 27648;             // 16*27*32 = 13824
    float* shp  = wp3 + 13824;             // 4*64
    float* sh0 = shp, *sh1 = shp + 64, *sh2 = shp + 128, *sh3 = shp + 192;

    // prep
    wprep<<<(110592 + 255) / 256, 256, 0, stream>>>(w0, bn0, wp0, 64, 64, 0);
    wprep<<<(55296 + 255) / 256, 256, 0, stream>>>(w1, bn1, wp1, 32, 64, 1);
    wprep<<<(27648 + 255) / 256, 256, 0, stream>>>(w2, bn2, wp2, 32, 32, 0);
    wprep<<<(13824 + 255) / 256, 256, 0, stream>>>(w3, bn3, wp3, 16, 32, 1);
    bnprep<<<1, 64, 0, stream>>>(bn0, 64, sh0);
    bnprep<<<1, 64, 0, stream>>>(bn1, 64, sh1);
    bnprep<<<1, 64, 0, stream>>>(bn2, 32, sh2);
    bnprep<<<1, 64, 0, stream>>>(bn3, 32, sh3);

    // ---- layer 1: upsample(x) -> conv(w0) 64->64 @64x64, hidden 32, fwd ----
    conv_tile<64, 64, 64, 1, 0><<<dim3(2, 16, BB * DD), 256, 0, stream>>>(
        x, nullptr, wp0, sh0, bufG);
    qrnn_scan<<<(BB * 32 * 4096 + 255) / 256, 256, 0, stream>>>(bufG, bufH, 32, 4096, 0);

    // ---- layer 2: (h1+xs2) -> deconv(w1) 32->64 @64x64, hidden 32, rev ----
    conv_tile<32, 64, 64, 0, 1><<<dim3(2, 16, BB * DD), 256, 0, stream>>>(
        bufH, xs2, wp1, sh1, bufG);
    qrnn_scan<<<(BB * 32 * 4096 + 255) / 256, 256, 0, stream>>>(bufG, bufH, 32, 4096, 1);

    // ---- layer 3: upsample(h2+xs1) -> conv(w2) 32->32 @128x128, hidden 16, fwd ----
    conv_tile<32, 32, 128, 1, 1><<<dim3(4, 16, BB * DD), 256, 0, stream>>>(
        bufH, xs1, wp2, sh2, bufG);
    qrnn_scan<<<(BB * 16 * 16384 + 255) / 256, 256, 0, stream>>>(bufG, bufH, 16, 16384, 0);

    // ---- layer 4: (h3+xs0) -> deconv(w3) 16->32 @128x128, hidden 16, rev ----
    conv_tile<16, 32, 128, 0, 1><<<dim3(4, 16, BB * DD), 256, 0, stream>>>(
        bufH, xs0, wp3, sh3, bufG);
    qrnn_scan<<<(BB * 16 * 16384 + 255) / 256, 256, 0, stream>>>(bufG, out, 16, 16384, 1);
}

// Round 3
// 684.516 us; speedup vs baseline: 118.1046x; 6.1690x over previous
//
#include <hip/hip_runtime.h>
#include <math.h>

#define BB 4
#define DD 31

typedef _Float16 half8 __attribute__((ext_vector_type(8)));
typedef float f32x4 __attribute__((ext_vector_type(4)));

__device__ __forceinline__ int swz(int b) { return b ^ (((b >> 7) & 7) << 4); }

// ---------------- prep kernels ----------------

__global__ void bnprep(const float* __restrict__ bn, int C, float* __restrict__ sh) {
    int c = threadIdx.x;
    if (c >= C) return;
    float g = bn[c], b = bn[C + c], m = bn[2 * C + c], v = bn[3 * C + c];
    sh[c] = b - m * (g * rsqrtf(v + 1e-5f));
}

// wq[ko][co][ki] = W[k=ko*32+ki][co] * bnscale[co], k = tap*CIN + ci, zero-pad k>=27*CIN
// tr=0: W = src[co][ci][tap];  tr=1 (deconv): W = src[ci][co][26-tap]
__global__ void wprep(const float* __restrict__ src, const float* __restrict__ bn,
                      _Float16* __restrict__ dst, int CIN, int COUT, int KS, int tr) {
    int idx = blockIdx.x * 256 + threadIdx.x;
    int total = KS * 32 * COUT;
    if (idx >= total) return;
    int ki = idx % 32;
    int co = (idx / 32) % COUT;
    int ko = idx / (32 * COUT);
    int k = ko * 32 + ki;
    float v = 0.f;
    if (k < 27 * CIN) {
        int tap = k / CIN, ci = k % CIN;
        v = tr ? src[((size_t)ci * COUT + co) * 27 + (26 - tap)]
               : src[((size_t)co * CIN + ci) * 27 + tap];
        v *= bn[co] * rsqrtf(bn[3 * COUT + co] + 1e-5f);
    }
    dst[((size_t)ko * COUT + co) * 32 + ki] = (_Float16)v;
}

// x [4][64][31][1024] f32 NCDHW -> xf [4*31][1024][64] f16 NDHWC
__global__ __launch_bounds__(256) void xconv(const float* __restrict__ src,
                                             _Float16* __restrict__ dst) {
    int idx = blockIdx.x * 256 + threadIdx.x;
    if (idx >= 4 * 31 * 1024 * 8) return;
    int cb = idx & 7;
    int pos = (idx >> 3) & 1023;
    int bd = idx >> 13;            // b*31 + d
    int d = bd % 31, b = bd / 31;
    half8 v;
#pragma unroll
    for (int j = 0; j < 8; ++j)
        v[j] = (_Float16)src[(((size_t)b * 64 + cb * 8 + j) * 31 + d) * 1024 + pos];
    *(half8*)(dst + ((size_t)bd * 1024 + pos) * 64 + cb * 8) = v;
}

// ---------------- conv via MFMA ----------------
// Block: 16x16 spatial tile, ALL COUT, one (b,d). 4 waves; wave wv owns h-rows
// [wv*4, wv*4+4). A = input patch (LDS, swizzled NDHWC f16), B = weights (L2).
// acc[f][n]: m-fragment f (h-row), co-block n. K = CIN*27 linearized, 32/step.
template <int CIN, int COUT, int S, int UP, int KSTEPS>
__global__ __launch_bounds__(256, 2) void conv_mfma(
    const _Float16* __restrict__ inp,   // [B*DD][SIN][SIN][CIN] f16
    const _Float16* __restrict__ wq,    // [KSTEPS][COUT][32] f16
    const float* __restrict__ bnsh,
    _Float16* __restrict__ gout) {      // [B*DD][S][S][COUT] f16

    constexpr int SIN = UP ? S / 2 : S;
    constexpr int IH = UP ? 10 : 18;
    constexpr int IW = UP ? 10 : 18;
    constexpr int NCB = COUT / 16;
    constexpr int NC8 = CIN / 8;
    constexpr int PATCH = 3 * IH * IW;

    __shared__ __align__(16) _Float16 lin[PATCH * CIN];

    const int tid = threadIdx.x;
    const int lane = tid & 63;
    const int wv = tid >> 6;
    const int col = lane & 15;
    const int grp = lane >> 4;

    const int w0 = blockIdx.x * 16;
    const int h0 = blockIdx.y * 16;
    const int bz = blockIdx.z;          // b*DD + d
    const int d = bz % DD;

    const int ibh = (UP ? h0 / 2 : h0) - 1;
    const int ibw = (UP ? w0 / 2 : w0) - 1;

    // ---- stage 3 kd-planes of the input patch into swizzled LDS ----
    for (int idx = tid; idx < PATCH * NC8; idx += 256) {
        int c8 = idx % NC8;
        int pos = idx / NC8;
        int iw = pos % IW, t = pos / IW;
        int ih = t % IH, kd = t / IH;
        int dz = d + kd - 1, gh = ibh + ih, gw = ibw + iw;
        half8 v = {0, 0, 0, 0, 0, 0, 0, 0};
        if ((unsigned)dz < (unsigned)DD && (unsigned)gh < (unsigned)SIN &&
            (unsigned)gw < (unsigned)SIN)
            v = *(const half8*)(inp +
                (((size_t)(bz + kd - 1) * SIN + gh) * SIN + gw) * CIN + c8 * 8);
        *(half8*)((char*)lin + swz((pos * CIN + c8 * 8) * 2)) = v;
    }
    __syncthreads();

    f32x4 acc[4][NCB];
#pragma unroll
    for (int f = 0; f < 4; ++f)
#pragma unroll
        for (int n = 0; n < NCB; ++n) acc[f][n] = {0.f, 0.f, 0.f, 0.f};

    for (int ko = 0; ko < KSTEPS; ++ko) {
        int k0 = ko * 32 + grp * 8;
        int tap = k0 / CIN;             // CIN is power of 2
        int ci = k0 % CIN;
        if (KSTEPS * 32 > 27 * CIN) tap = tap > 26 ? 26 : tap;  // L4 zero-pad tail
        int kd = tap / 9, trm = tap % 9;
        int kh = trm / 3, kw = trm % 3;
        int iw = UP ? (((col + kw - 1) >> 1) + 1) : (col + kw);

        half8 a[4];
        if (UP) {
#pragma unroll
            for (int f = 0; f < 4; ++f) {
                int ih = ((h0 + wv * 4 + f + kh - 1) >> 1) - ibh;
                int by = (((kd * IH + ih) * IW + iw) * CIN + ci) * 2;
                a[f] = *(const half8*)((const char*)lin + swz(by));
            }
        } else {
            int by0 = (((kd * IH + wv * 4 + kh) * IW + iw) * CIN + ci) * 2;
#pragma unroll
            for (int f = 0; f < 4; ++f)
                a[f] = *(const half8*)((const char*)lin + swz(by0 + f * (IW * CIN * 2)));
        }
        half8 bfr[NCB];
#pragma unroll
        for (int n = 0; n < NCB; ++n)
            bfr[n] = *(const half8*)(wq + ((ko * COUT + n * 16 + col) * 32 + grp * 8));
#pragma unroll
        for (int f = 0; f < 4; ++f)
#pragma unroll
            for (int n = 0; n < NCB; ++n)
                acc[f][n] = __builtin_amdgcn_mfma_f32_16x16x32_f16(a[f], bfr[n],
                                                                   acc[f][n], 0, 0, 0);
    }

    // ---- epilogue: +shift, act, f16 store (NDHWC) ----
    const size_t obase = (size_t)bz * S * S * COUT;
#pragma unroll
    for (int n = 0; n < NCB; ++n) {
        int co = n * 16 + col;
        float sh = bnsh[co];
#pragma unroll
        for (int f = 0; f < 4; ++f) {
            int h = h0 + wv * 4 + f;
#pragma unroll
            for (int r = 0; r < 4; ++r) {
                int w = w0 + grp * 4 + r;
                float y = acc[f][n][r] + sh;
                float v = (n < NCB / 2) ? tanhf(y) : 1.f / (1.f + __expf(-y));
                gout[obase + ((size_t)h * S + w) * COUT + co] = (_Float16)v;
            }
        }
    }
}

// ---------------- fused qrnn scan (+skip add) ----------------
// g [B*DD][HW][2H] f16. MID: hout [B*DD][HW][H] f16 = h + xs (xs f32 NCDHW).
// LAST: fout [B][H][DD][HW] f32 = h.
template <int H, int HW, int LAST>
__global__ __launch_bounds__(256) void qscan(
    const _Float16* __restrict__ g, const float* __restrict__ xs,
    _Float16* __restrict__ hout, float* __restrict__ fout, int rev) {
    constexpr int NCB = H / 8;
    int idx = blockIdx.x * 256 + threadIdx.x;
    if (idx >= BB * HW * NCB) return;
    int cb = idx % NCB;
    int hw = (idx / NCB) % HW;
    int b = idx / (NCB * HW);
    int c0 = cb * 8;

    float h[8];
#pragma unroll
    for (int j = 0; j < 8; ++j) h[j] = 0.f;

    for (int t = 0; t < DD; ++t) {
        int d = rev ? (DD - 1 - t) : t;
        const _Float16* gp = g + ((size_t)(b * DD + d) * HW + hw) * (2 * H);
        half8 z8 = *(const half8*)(gp + c0);
        half8 f8 = *(const half8*)(gp + H + c0);
        if (LAST) {
#pragma unroll
            for (int j = 0; j < 8; ++j) {
                float fv = (float)f8[j];
                h[j] = fv * h[j] + (1.f - fv) * (float)z8[j];
                fout[(((size_t)b * H + c0 + j) * DD + d) * HW + hw] = h[j];
            }
        } else {
            half8 o;
#pragma unroll
            for (int j = 0; j < 8; ++j) {
                float fv = (float)f8[j];
                h[j] = fv * h[j] + (1.f - fv) * (float)z8[j];
                o[j] = (_Float16)(h[j] + xs[(((size_t)b * H + c0 + j) * DD + d) * HW + hw]);
            }
            *(half8*)(hout + ((size_t)(b * DD + d) * HW + hw) * H + c0) = o;
        }
    }
}

extern "C" void kernel_launch(void* const* d_in, const int* in_sizes, int n_in,
                              void* d_out, int out_size, void* d_ws, size_t ws_size,
                              hipStream_t stream) {
    const float* x   = (const float*)d_in[0];
    const float* xs0 = (const float*)d_in[1];
    const float* xs1 = (const float*)d_in[2];
    const float* xs2 = (const float*)d_in[3];
    const float* w0  = (const float*)d_in[4];
    const float* w1  = (const float*)d_in[5];
    const float* w2  = (const float*)d_in[6];
    const float* w3  = (const float*)d_in[7];
    const float* bn0 = (const float*)d_in[8];
    const float* bn1 = (const float*)d_in[9];
    const float* bn2 = (const float*)d_in[10];
    const float* bn3 = (const float*)d_in[11];
    float* out = (float*)d_out;

    // ---- workspace layout ----
    char* p = (char*)d_ws;
    _Float16* xf = (_Float16*)p;  p += (size_t)124 * 1024 * 64 * 2;     // 16.25 MB
    _Float16* gA = (_Float16*)p;  p += (size_t)124 * 4096 * 64 * 2;     // 65 MB
    _Float16* hA = (_Float16*)p;  p += (size_t)124 * 4096 * 32 * 2;     // 32.5 MB
    _Float16* gB = (_Float16*)p;  p += (size_t)124 * 16384 * 32 * 2;    // 130 MB
    _Float16* hB = (_Float16*)p;  p += (size_t)124 * 16384 * 16 * 2;    // 65 MB
    _Float16* wq0 = (_Float16*)p; p += 54 * 64 * 32 * 2;
    _Float16* wq1 = (_Float16*)p; p += 27 * 64 * 32 * 2;
    _Float16* wq2 = (_Float16*)p; p += 27 * 32 * 32 * 2;
    _Float16* wq3 = (_Float16*)p; p += 14 * 32 * 32 * 2;
    float* sh0 = (float*)p;       p += 64 * 4;
    float* sh1 = (float*)p;       p += 64 * 4;
    float* sh2 = (float*)p;       p += 64 * 4;
    float* sh3 = (float*)p;       p += 64 * 4;

    // ---- prep ----
    xconv<<<(4 * 31 * 1024 * 8 + 255) / 256, 256, 0, stream>>>(x, xf);
    wprep<<<(54 * 32 * 64 + 255) / 256, 256, 0, stream>>>(w0, bn0, wq0, 64, 64, 54, 0);
    wprep<<<(27 * 32 * 64 + 255) / 256, 256, 0, stream>>>(w1, bn1, wq1, 32, 64, 27, 1);
    wprep<<<(27 * 32 * 32 + 255) / 256, 256, 0, stream>>>(w2, bn2, wq2, 32, 32, 27, 0);
    wprep<<<(14 * 32 * 32 + 255) / 256, 256, 0, stream>>>(w3, bn3, wq3, 16, 32, 14, 1);
    bnprep<<<1, 64, 0, stream>>>(bn0, 64, sh0);
    bnprep<<<1, 64, 0, stream>>>(bn1, 64, sh1);
    bnprep<<<1, 64, 0, stream>>>(bn2, 32, sh2);
    bnprep<<<1, 64, 0, stream>>>(bn3, 32, sh3);

    // ---- layer 1: up(x) -> conv w0 (64->64) @64, fwd; h1 += xs2 ----
    conv_mfma<64, 64, 64, 1, 54><<<dim3(4, 4, BB * DD), 256, 0, stream>>>(xf, wq0, sh0, gA);
    qscan<32, 4096, 0><<<(BB * 4096 * 4 + 255) / 256, 256, 0, stream>>>(gA, xs2, hA, nullptr, 0);

    // ---- layer 2: deconv w1 (32->64) @64, rev; h2 += xs1 ----
    conv_mfma<32, 64, 64, 0, 27><<<dim3(4, 4, BB * DD), 256, 0, stream>>>(hA, wq1, sh1, gA);
    qscan<32, 4096, 0><<<(BB * 4096 * 4 + 255) / 256, 256, 0, stream>>>(gA, xs1, hA, nullptr, 1);

    // ---- layer 3: up -> conv w2 (32->32) @128, fwd; h3 += xs0 ----
    conv_mfma<32, 32, 128, 1, 27><<<dim3(8, 8, BB * DD), 256, 0, stream>>>(hA, wq2, sh2, gB);
    qscan<16, 16384, 0><<<(BB * 16384 * 2 + 255) / 256, 256, 0, stream>>>(gB, xs0, hB, nullptr, 0);

    // ---- layer 4: deconv w3 (16->32) @128, rev; out fp32 ----
    conv_mfma<16, 32, 128, 0, 14><<<dim3(8, 8, BB * DD), 256, 0, stream>>>(hB, wq3, sh3, gB);
    qscan<16, 16384, 1><<<(BB * 16384 * 2 + 255) / 256, 256, 0, stream>>>(gB, nullptr, nullptr, out, 1);
}

// Round 4
// 651.537 us; speedup vs baseline: 124.0827x; 1.0506x over previous
//
#include <hip/hip_runtime.h>
#include <math.h>

#define BB 4
#define DD 31

typedef _Float16 half8 __attribute__((ext_vector_type(8)));
typedef float f32x4 __attribute__((ext_vector_type(4)));

__device__ __forceinline__ int swz(int b) { return b ^ (((b >> 7) & 7) << 4); }

__device__ __forceinline__ half8 ldswz(const _Float16* lin, int byteoff) {
    return *(const half8*)((const char*)lin + swz(byteoff));
}

__device__ __forceinline__ float fast_tanh(float y) {
    float e = __expf(2.f * y);
    return 1.f - 2.f * __builtin_amdgcn_rcpf(e + 1.f);
}
__device__ __forceinline__ float fast_sigmoid(float y) {
    return __builtin_amdgcn_rcpf(1.f + __expf(-y));
}

// ---------------- prep kernels ----------------

__global__ void bnprep(const float* __restrict__ bn, int C, float* __restrict__ sh) {
    int c = threadIdx.x;
    if (c >= C) return;
    float g = bn[c], b = bn[C + c], m = bn[2 * C + c], v = bn[3 * C + c];
    sh[c] = b - m * (g * rsqrtf(v + 1e-5f));
}

// wq[ko][co][ki] = W[k=ko*32+ki][co] * bnscale[co], k = tap*CIN + ci, zero-pad k>=27*CIN
// tr=0: W = src[co][ci][tap];  tr=1 (deconv): W = src[ci][co][26-tap]
__global__ void wprep(const float* __restrict__ src, const float* __restrict__ bn,
                      _Float16* __restrict__ dst, int CIN, int COUT, int KS, int tr) {
    int idx = blockIdx.x * 256 + threadIdx.x;
    int total = KS * 32 * COUT;
    if (idx >= total) return;
    int ki = idx % 32;
    int co = (idx / 32) % COUT;
    int ko = idx / (32 * COUT);
    int k = ko * 32 + ki;
    float v = 0.f;
    if (k < 27 * CIN) {
        int tap = k / CIN, ci = k % CIN;
        v = tr ? src[((size_t)ci * COUT + co) * 27 + (26 - tap)]
               : src[((size_t)co * CIN + ci) * 27 + tap];
        v *= bn[co] * rsqrtf(bn[3 * COUT + co] + 1e-5f);
    }
    dst[((size_t)ko * COUT + co) * 32 + ki] = (_Float16)v;
}

// x [4][64][31][1024] f32 NCDHW -> xf [4*31][1024][64] f16 NDHWC
__global__ __launch_bounds__(256) void xconv(const float* __restrict__ src,
                                             _Float16* __restrict__ dst) {
    int idx = blockIdx.x * 256 + threadIdx.x;
    if (idx >= 4 * 31 * 1024 * 8) return;
    int cb = idx & 7;
    int pos = (idx >> 3) & 1023;
    int bd = idx >> 13;            // b*31 + d
    int d = bd % 31, b = bd / 31;
    half8 v;
#pragma unroll
    for (int j = 0; j < 8; ++j)
        v[j] = (_Float16)src[(((size_t)b * 64 + cb * 8 + j) * 31 + d) * 1024 + pos];
    *(half8*)(dst + ((size_t)bd * 1024 + pos) * 64 + cb * 8) = v;
}

// ---------------- conv via MFMA ----------------
// Block: 16x16 spatial tile, ALL COUT, one (b,d). 4 waves; wave wv owns h-rows
// [wv*4, wv*4+4). A = input patch (LDS, swizzled NDHWC f16), B = weights (L2).
// MFMA m-dim = w (col lane), n-dim = co; acc[f][n]: f = h-row, n = co-block.
// K = CIN*27 linearized tap-major, 32/step. ko loop FULLY UNROLLED so the
// tap->(kd,kh,kw) decode constant-folds (CIN>=32: literal; CIN==16: 2-way select).
template <int CIN, int COUT, int S, int UP, int KSTEPS>
__global__ __launch_bounds__(256, 2) void conv_mfma(
    const _Float16* __restrict__ inp,   // [B*DD][SIN][SIN][CIN] f16
    const _Float16* __restrict__ wq,    // [KSTEPS][COUT][32] f16
    const float* __restrict__ bnsh,
    _Float16* __restrict__ gout) {      // [B*DD][S][S][COUT] f16

    constexpr int SIN = UP ? S / 2 : S;
    constexpr int IH = UP ? 10 : 18;
    constexpr int IW = UP ? 10 : 18;
    constexpr int NCB = COUT / 16;
    constexpr int NC8 = CIN / 8;
    constexpr int PATCH = 3 * IH * IW;

    __shared__ __align__(16) _Float16 lin[PATCH * CIN];

    const int tid = threadIdx.x;
    const int lane = tid & 63;
    const int wv = tid >> 6;
    const int col = lane & 15;
    const int grp = lane >> 4;

    const int w0 = blockIdx.x * 16;
    const int h0 = blockIdx.y * 16;
    const int bz = blockIdx.z;          // b*DD + d
    const int d = bz % DD;

    const int ibh = (UP ? h0 / 2 : h0) - 1;
    const int ibw = (UP ? w0 / 2 : w0) - 1;

    // ---- stage 3 kd-planes of the input patch into swizzled LDS ----
    for (int idx = tid; idx < PATCH * NC8; idx += 256) {
        int c8 = idx % NC8;
        int pos = idx / NC8;
        int iw = pos % IW, t = pos / IW;
        int ih = t % IH, kd = t / IH;
        int dz = d + kd - 1, gh = ibh + ih, gw = ibw + iw;
        half8 v = {0, 0, 0, 0, 0, 0, 0, 0};
        if ((unsigned)dz < (unsigned)DD && (unsigned)gh < (unsigned)SIN &&
            (unsigned)gw < (unsigned)SIN)
            v = *(const half8*)(inp +
                (((size_t)(bz + kd - 1) * SIN + gh) * SIN + gw) * CIN + c8 * 8);
        *(half8*)((char*)lin + swz((pos * CIN + c8 * 8) * 2)) = v;
    }
    __syncthreads();

    f32x4 acc[4][NCB];
#pragma unroll
    for (int f = 0; f < 4; ++f)
#pragma unroll
        for (int n = 0; n < NCB; ++n) acc[f][n] = {0.f, 0.f, 0.f, 0.f};

#pragma unroll
    for (int ko = 0; ko < KSTEPS; ++ko) {
        int kd, kh, kw, ci;
        if (CIN >= 32) {
            int tap = (ko * 32) / CIN;                  // literal after unroll
            kd = tap / 9; kh = (tap / 3) % 3; kw = tap % 3;
            ci = (ko * 32) % CIN + grp * 8;
        } else {                                        // CIN==16: 2 taps per step
            int t0 = (2 * ko < 27) ? 2 * ko : 26;
            int t1 = (2 * ko + 1 < 27) ? 2 * ko + 1 : 26;
            int hi = grp >> 1;
            kd = hi ? t1 / 9 : t0 / 9;
            kh = hi ? (t1 / 3) % 3 : (t0 / 3) % 3;
            kw = hi ? t1 % 3 : t0 % 3;
            ci = (grp & 1) * 8;
        }

        half8 a[4];
        if (UP) {
            int iw = ((col + kw - 1) >> 1) + 1;
            // lds rows (h0 cancels): kh=0 -> r0=2wv, map {L0,L1,L1,L2}
            //                        kh=1 -> r0=2wv+1, map {L0,L0,L1,L1}
            //                        kh=2 -> r0=2wv+1, map {L0,L1,L1,L2}
            int r0 = 2 * wv + (kh == 0 ? 0 : 1);
            int cb = ((kd * IH + r0) * IW + iw) * CIN + ci;
            half8 l0 = ldswz(lin, cb * 2);
            half8 l1 = ldswz(lin, (cb + IW * CIN) * 2);
            if (kh == 1) {
                a[0] = l0; a[1] = l0; a[2] = l1; a[3] = l1;
            } else {
                half8 l2 = ldswz(lin, (cb + 2 * IW * CIN) * 2);
                a[0] = l0; a[1] = l1; a[2] = l1; a[3] = l2;
            }
        } else {
            int iw = col + kw;
            int cb = ((kd * IH + wv * 4 + kh) * IW + iw) * CIN + ci;
#pragma unroll
            for (int f = 0; f < 4; ++f)
                a[f] = ldswz(lin, (cb + f * IW * CIN) * 2);
        }

        half8 bfr[NCB];
#pragma unroll
        for (int n = 0; n < NCB; ++n)
            bfr[n] = *(const half8*)(wq + ((ko * COUT + n * 16 + col) * 32 + grp * 8));
#pragma unroll
        for (int f = 0; f < 4; ++f)
#pragma unroll
            for (int n = 0; n < NCB; ++n)
                acc[f][n] = __builtin_amdgcn_mfma_f32_16x16x32_f16(a[f], bfr[n],
                                                                   acc[f][n], 0, 0, 0);
    }

    // ---- epilogue: +shift, act, f16 store (NDHWC) ----
    const size_t obase = (size_t)bz * S * S * COUT;
#pragma unroll
    for (int n = 0; n < NCB; ++n) {
        int co = n * 16 + col;
        float sh = bnsh[co];
#pragma unroll
        for (int f = 0; f < 4; ++f) {
            int h = h0 + wv * 4 + f;
#pragma unroll
            for (int r = 0; r < 4; ++r) {
                int w = w0 + grp * 4 + r;
                float y = acc[f][n][r] + sh;
                float v = (n < NCB / 2) ? fast_tanh(y) : fast_sigmoid(y);
                gout[obase + ((size_t)h * S + w) * COUT + co] = (_Float16)v;
            }
        }
    }
}

// ---------------- fused qrnn scan (+skip add) ----------------
// g [B*DD][HW][2H] f16. MID: hout [B*DD][HW][H] f16 = h + xs (xs f32 NCDHW).
// LAST: fout [B][H][DD][HW] f32 = h.
template <int H, int HW, int LAST>
__global__ __launch_bounds__(256) void qscan(
    const _Float16* __restrict__ g, const float* __restrict__ xs,
    _Float16* __restrict__ hout, float* __restrict__ fout, int rev) {
    constexpr int NCB = H / 8;
    int idx = blockIdx.x * 256 + threadIdx.x;
    if (idx >= BB * HW * NCB) return;
    int cb = idx % NCB;
    int hw = (idx / NCB) % HW;
    int b = idx / (NCB * HW);
    int c0 = cb * 8;

    float h[8];
#pragma unroll
    for (int j = 0; j < 8; ++j) h[j] = 0.f;

    for (int t = 0; t < DD; ++t) {
        int d = rev ? (DD - 1 - t) : t;
        const _Float16* gp = g + ((size_t)(b * DD + d) * HW + hw) * (2 * H);
        half8 z8 = *(const half8*)(gp + c0);
        half8 f8 = *(const half8*)(gp + H + c0);
        if (LAST) {
#pragma unroll
            for (int j = 0; j < 8; ++j) {
                float fv = (float)f8[j];
                h[j] = fv * h[j] + (1.f - fv) * (float)z8[j];
                fout[(((size_t)b * H + c0 + j) * DD + d) * HW + hw] = h[j];
            }
        } else {
            half8 o;
#pragma unroll
            for (int j = 0; j < 8; ++j) {
                float fv = (float)f8[j];
                h[j] = fv * h[j] + (1.f - fv) * (float)z8[j];
                o[j] = (_Float16)(h[j] + xs[(((size_t)b * H + c0 + j) * DD + d) * HW + hw]);
            }
            *(half8*)(hout + ((size_t)(b * DD + d) * HW + hw) * H + c0) = o;
        }
    }
}

extern "C" void kernel_launch(void* const* d_in, const int* in_sizes, int n_in,
                              void* d_out, int out_size, void* d_ws, size_t ws_size,
                              hipStream_t stream) {
    const float* x   = (const float*)d_in[0];
    const float* xs0 = (const float*)d_in[1];
    const float* xs1 = (const float*)d_in[2];
    const float* xs2 = (const float*)d_in[3];
    const float* w0  = (const float*)d_in[4];
    const float* w1  = (const float*)d_in[5];
    const float* w2  = (const float*)d_in[6];
    const float* w3  = (const float*)d_in[7];
    const float* bn0 = (const float*)d_in[8];
    const float* bn1 = (const float*)d_in[9];
    const float* bn2 = (const float*)d_in[10];
    const float* bn3 = (const float*)d_in[11];
    float* out = (float*)d_out;

    // ---- workspace layout ----
    char* p = (char*)d_ws;
    _Float16* xf = (_Float16*)p;  p += (size_t)124 * 1024 * 64 * 2;     // 16.25 MB
    _Float16* gA = (_Float16*)p;  p += (size_t)124 * 4096 * 64 * 2;     // 65 MB
    _Float16* hA = (_Float16*)p;  p += (size_t)124 * 4096 * 32 * 2;     // 32.5 MB
    _Float16* gB = (_Float16*)p;  p += (size_t)124 * 16384 * 32 * 2;    // 130 MB
    _Float16* hB = (_Float16*)p;  p += (size_t)124 * 16384 * 16 * 2;    // 65 MB
    _Float16* wq0 = (_Float16*)p; p += 54 * 64 * 32 * 2;
    _Float16* wq1 = (_Float16*)p; p += 27 * 64 * 32 * 2;
    _Float16* wq2 = (_Float16*)p; p += 27 * 32 * 32 * 2;
    _Float16* wq3 = (_Float16*)p; p += 14 * 32 * 32 * 2;
    float* sh0 = (float*)p;       p += 64 * 4;
    float* sh1 = (float*)p;       p += 64 * 4;
    float* sh2 = (float*)p;       p += 64 * 4;
    float* sh3 = (float*)p;       p += 64 * 4;

    // ---- prep ----
    xconv<<<(4 * 31 * 1024 * 8 + 255) / 256, 256, 0, stream>>>(x, xf);
    wprep<<<(54 * 32 * 64 + 255) / 256, 256, 0, stream>>>(w0, bn0, wq0, 64, 64, 54, 0);
    wprep<<<(27 * 32 * 64 + 255) / 256, 256, 0, stream>>>(w1, bn1, wq1, 32, 64, 27, 1);
    wprep<<<(27 * 32 * 32 + 255) / 256, 256, 0, stream>>>(w2, bn2, wq2, 32, 32, 27, 0);
    wprep<<<(14 * 32 * 32 + 255) / 256, 256, 0, stream>>>(w3, bn3, wq3, 16, 32, 14, 1);
    bnprep<<<1, 64, 0, stream>>>(bn0, 64, sh0);
    bnprep<<<1, 64, 0, stream>>>(bn1, 64, sh1);
    bnprep<<<1, 64, 0, stream>>>(bn2, 32, sh2);
    bnprep<<<1, 64, 0, stream>>>(bn3, 32, sh3);

    // ---- layer 1: up(x) -> conv w0 (64->64) @64, fwd; h1 += xs2 ----
    conv_mfma<64, 64, 64, 1, 54><<<dim3(4, 4, BB * DD), 256, 0, stream>>>(xf, wq0, sh0, gA);
    qscan<32, 4096, 0><<<(BB * 4096 * 4 + 255) / 256, 256, 0, stream>>>(gA, xs2, hA, nullptr, 0);

    // ---- layer 2: deconv w1 (32->64) @64, rev; h2 += xs1 ----
    conv_mfma<32, 64, 64, 0, 27><<<dim3(4, 4, BB * DD), 256, 0, stream>>>(hA, wq1, sh1, gA);
    qscan<32, 4096, 0><<<(BB * 4096 * 4 + 255) / 256, 256, 0, stream>>>(gA, xs1, hA, nullptr, 1);

    // ---- layer 3: up -> conv w2 (32->32) @128, fwd; h3 += xs0 ----
    conv_mfma<32, 32, 128, 1, 27><<<dim3(8, 8, BB * DD), 256, 0, stream>>>(hA, wq2, sh2, gB);
    qscan<16, 16384, 0><<<(BB * 16384 * 2 + 255) / 256, 256, 0, stream>>>(gB, xs0, hB, nullptr, 0);

    // ---- layer 4: deconv w3 (16->32) @128, rev; out fp32 ----
    conv_mfma<16, 32, 128, 0, 14><<<dim3(8, 8, BB * DD), 256, 0, stream>>>(hB, wq3, sh3, gB);
    qscan<16, 16384, 1><<<(BB * 16384 * 2 + 255) / 256, 256, 0, stream>>>(gB, nullptr, nullptr, out, 1);
}

// Round 5
// 567.084 us; speedup vs baseline: 142.5617x; 1.1489x over previous
//
#include <hip/hip_runtime.h>
#include <math.h>

#define BB 4
#define DD 31

typedef _Float16 half8 __attribute__((ext_vector_type(8)));
typedef float f32x4 __attribute__((ext_vector_type(4)));

__device__ __forceinline__ int swz(int b) { return b ^ (((b >> 7) & 7) << 4); }

__device__ __forceinline__ half8 ldswz(const _Float16* lin, int byteoff) {
    return *(const half8*)((const char*)lin + swz(byteoff));
}

__device__ __forceinline__ float fast_tanh(float y) {
    float e = __expf(2.f * y);
    return 1.f - 2.f * __builtin_amdgcn_rcpf(e + 1.f);
}
__device__ __forceinline__ float fast_sigmoid(float y) {
    return __builtin_amdgcn_rcpf(1.f + __expf(-y));
}

// ---------------- prep kernels ----------------

__global__ void bnprep(const float* __restrict__ bn, int C, float* __restrict__ sh) {
    int c = threadIdx.x;
    if (c >= C) return;
    float g = bn[c], b = bn[C + c], m = bn[2 * C + c], v = bn[3 * C + c];
    sh[c] = b - m * (g * rsqrtf(v + 1e-5f));
}

// wq[ko][co][ki] = W[k=ko*32+ki][co] * bnscale[co], k = tap*CIN + ci, zero-pad k>=27*CIN
// tr=0: W = src[co][ci][tap];  tr=1 (deconv): W = src[ci][co][26-tap]
__global__ void wprep(const float* __restrict__ src, const float* __restrict__ bn,
                      _Float16* __restrict__ dst, int CIN, int COUT, int KS, int tr) {
    int idx = blockIdx.x * 256 + threadIdx.x;
    int total = KS * 32 * COUT;
    if (idx >= total) return;
    int ki = idx % 32;
    int co = (idx / 32) % COUT;
    int ko = idx / (32 * COUT);
    int k = ko * 32 + ki;
    float v = 0.f;
    if (k < 27 * CIN) {
        int tap = k / CIN, ci = k % CIN;
        v = tr ? src[((size_t)ci * COUT + co) * 27 + (26 - tap)]
               : src[((size_t)co * CIN + ci) * 27 + tap];
        v *= bn[co] * rsqrtf(bn[3 * COUT + co] + 1e-5f);
    }
    dst[((size_t)ko * COUT + co) * 32 + ki] = (_Float16)v;
}

// Collapsed upsample-conv weights (conv layout src[co][ci][27], never deconv).
// wqu[par][ko][co][ki]; k = ko*32+ki = tap*CIN+ci; tap = (kd*2+ih)*2+iw.
// weight = sum_{kh,kw} c[ph][ih][kh]*c[pw][iw][kw]*src[co][ci][kd*9+kh*3+kw]*bnscale
__global__ void wprep_up(const float* __restrict__ src, const float* __restrict__ bn,
                         _Float16* __restrict__ dst, int CIN, int COUT) {
    const int KS = 12 * CIN / 32;
    int idx = blockIdx.x * 256 + threadIdx.x;
    int total = 4 * KS * 32 * COUT;
    if (idx >= total) return;
    int ki = idx % 32;
    int co = (idx / 32) % COUT;
    int ko = (idx / (32 * COUT)) % KS;
    int par = idx / (32 * COUT * KS);
    int k = ko * 32 + ki;
    int ci = k % CIN, tap = k / CIN;
    int kd = tap >> 2, ih = (tap >> 1) & 1, iw = tap & 1;
    int ph = par >> 1, pw = par & 1;
    const float c[2][2][3] = {{{1, 0, 0}, {0, 1, 1}}, {{1, 1, 0}, {0, 0, 1}}};
    float v = 0.f;
    for (int kh = 0; kh < 3; ++kh)
        for (int kw = 0; kw < 3; ++kw)
            v += c[ph][ih][kh] * c[pw][iw][kw] *
                 src[((size_t)co * CIN + ci) * 27 + kd * 9 + kh * 3 + kw];
    v *= bn[co] * rsqrtf(bn[3 * COUT + co] + 1e-5f);
    dst[(((size_t)par * KS + ko) * COUT + co) * 32 + ki] = (_Float16)v;
}

// x [4][64][31][1024] f32 NCDHW -> xf [4*31][1024][64] f16 NDHWC
__global__ __launch_bounds__(256) void xconv(const float* __restrict__ src,
                                             _Float16* __restrict__ dst) {
    int idx = blockIdx.x * 256 + threadIdx.x;
    if (idx >= 4 * 31 * 1024 * 8) return;
    int cb = idx & 7;
    int pos = (idx >> 3) & 1023;
    int bd = idx >> 13;            // b*31 + d
    int d = bd % 31, b = bd / 31;
    half8 v;
#pragma unroll
    for (int j = 0; j < 8; ++j)
        v[j] = (_Float16)src[(((size_t)b * 64 + cb * 8 + j) * 31 + d) * 1024 + pos];
    *(half8*)(dst + ((size_t)bd * 1024 + pos) * 64 + cb * 8) = v;
}

// ---------------- non-upsample conv via MFMA (layers 2,4) ----------------
template <int CIN, int COUT, int S, int KSTEPS>
__global__ __launch_bounds__(256, 2) void conv_mfma(
    const _Float16* __restrict__ inp,   // [B*DD][S][S][CIN] f16
    const _Float16* __restrict__ wq,    // [KSTEPS][COUT][32] f16
    const float* __restrict__ bnsh,
    _Float16* __restrict__ gout) {      // [B*DD][S][S][COUT] f16

    constexpr int IH = 18;
    constexpr int IW = 18;
    constexpr int NCB = COUT / 16;
    constexpr int NC8 = CIN / 8;
    constexpr int PATCH = 3 * IH * IW;

    __shared__ __align__(16) _Float16 lin[PATCH * CIN];

    const int tid = threadIdx.x;
    const int lane = tid & 63;
    const int wv = tid >> 6;
    const int col = lane & 15;
    const int grp = lane >> 4;

    const int w0 = blockIdx.x * 16;
    const int h0 = blockIdx.y * 16;
    const int bz = blockIdx.z;          // b*DD + d
    const int d = bz % DD;

    const int ibh = h0 - 1;
    const int ibw = w0 - 1;

    for (int idx = tid; idx < PATCH * NC8; idx += 256) {
        int c8 = idx % NC8;
        int pos = idx / NC8;
        int iw = pos % IW, t = pos / IW;
        int ih = t % IH, kd = t / IH;
        int dz = d + kd - 1, gh = ibh + ih, gw = ibw + iw;
        half8 v = {0, 0, 0, 0, 0, 0, 0, 0};
        if ((unsigned)dz < (unsigned)DD && (unsigned)gh < (unsigned)S &&
            (unsigned)gw < (unsigned)S)
            v = *(const half8*)(inp +
                (((size_t)(bz + kd - 1) * S + gh) * S + gw) * CIN + c8 * 8);
        *(half8*)((char*)lin + swz((pos * CIN + c8 * 8) * 2)) = v;
    }
    __syncthreads();

    f32x4 acc[4][NCB];
#pragma unroll
    for (int f = 0; f < 4; ++f)
#pragma unroll
        for (int n = 0; n < NCB; ++n) acc[f][n] = {0.f, 0.f, 0.f, 0.f};

#pragma unroll
    for (int ko = 0; ko < KSTEPS; ++ko) {
        int kd, kh, kw, ci;
        if (CIN >= 32) {
            int tap = (ko * 32) / CIN;                  // literal after unroll
            kd = tap / 9; kh = (tap / 3) % 3; kw = tap % 3;
            ci = (ko * 32) % CIN + grp * 8;
        } else {                                        // CIN==16: 2 taps per step
            int t0 = (2 * ko < 27) ? 2 * ko : 26;
            int t1 = (2 * ko + 1 < 27) ? 2 * ko + 1 : 26;
            int hi = grp >> 1;
            kd = hi ? t1 / 9 : t0 / 9;
            kh = hi ? (t1 / 3) % 3 : (t0 / 3) % 3;
            kw = hi ? t1 % 3 : t0 % 3;
            ci = (grp & 1) * 8;
        }

        half8 a[4];
        int iw = col + kw;
        int cb = ((kd * IH + wv * 4 + kh) * IW + iw) * CIN + ci;
#pragma unroll
        for (int f = 0; f < 4; ++f)
            a[f] = ldswz(lin, (cb + f * IW * CIN) * 2);

        half8 bfr[NCB];
#pragma unroll
        for (int n = 0; n < NCB; ++n)
            bfr[n] = *(const half8*)(wq + ((ko * COUT + n * 16 + col) * 32 + grp * 8));
#pragma unroll
        for (int f = 0; f < 4; ++f)
#pragma unroll
            for (int n = 0; n < NCB; ++n)
                acc[f][n] = __builtin_amdgcn_mfma_f32_16x16x32_f16(a[f], bfr[n],
                                                                   acc[f][n], 0, 0, 0);
    }

    const size_t obase = (size_t)bz * S * S * COUT;
#pragma unroll
    for (int n = 0; n < NCB; ++n) {
        int co = n * 16 + col;
        float sh = bnsh[co];
#pragma unroll
        for (int f = 0; f < 4; ++f) {
            int h = h0 + wv * 4 + f;
#pragma unroll
            for (int r = 0; r < 4; ++r) {
                int w = w0 + grp * 4 + r;
                float y = acc[f][n][r] + sh;
                float v = (n < NCB / 2) ? fast_tanh(y) : fast_sigmoid(y);
                gout[obase + ((size_t)h * S + w) * COUT + co] = (_Float16)v;
            }
        }
    }
}

// ---------------- collapsed upsample-conv via MFMA (layers 1,3) ----------------
// Output tile 32(w) x 8(h); wave = one parity (ph=wv>>1, pw=wv&1):
// 16 w' (m=col) x 4 h' (f). Input patch at ORIGINAL resolution:
// [3kd][6][18][CIN], K = CIN*12 (kd,ih,iw per parity), KS = 12*CIN/32 steps.
template <int CIN, int COUT, int S, int MINW>
__global__ __launch_bounds__(256, MINW) void conv_up(
    const _Float16* __restrict__ inp,   // [B*DD][S/2][S/2][CIN] f16
    const _Float16* __restrict__ wqu,   // [4][KS][COUT][32] f16
    const float* __restrict__ bnsh,
    _Float16* __restrict__ gout) {      // [B*DD][S][S][COUT] f16

    constexpr int SIN = S / 2;
    constexpr int KS = 12 * CIN / 32;
    constexpr int NCB = COUT / 16;
    constexpr int NC8 = CIN / 8;
    constexpr int IH = 6, IW = 18;
    constexpr int PATCH = 3 * IH * IW;

    __shared__ __align__(16) _Float16 lin[PATCH * CIN];

    const int tid = threadIdx.x;
    const int lane = tid & 63;
    const int wv = tid >> 6;
    const int col = lane & 15;
    const int grp = lane >> 4;
    const int ph = wv >> 1, pw = wv & 1;

    const int bwp = blockIdx.x * 16;    // base w' (orig res)
    const int bhp = blockIdx.y * 4;     // base h'
    const int bz = blockIdx.z;
    const int d = bz % DD;

    // stage patch, origin (bhp-1, bwp-1)
    for (int idx = tid; idx < PATCH * NC8; idx += 256) {
        int c8 = idx % NC8;
        int pos = idx / NC8;
        int iwp = pos % IW, t = pos / IW;
        int ihp = t % IH, kd = t / IH;
        int dz = d + kd - 1, gh = bhp - 1 + ihp, gw = bwp - 1 + iwp;
        half8 v = {0, 0, 0, 0, 0, 0, 0, 0};
        if ((unsigned)dz < (unsigned)DD && (unsigned)gh < (unsigned)SIN &&
            (unsigned)gw < (unsigned)SIN)
            v = *(const half8*)(inp +
                (((size_t)(bz + kd - 1) * SIN + gh) * SIN + gw) * CIN + c8 * 8);
        *(half8*)((char*)lin + swz((pos * CIN + c8 * 8) * 2)) = v;
    }
    __syncthreads();

    f32x4 acc[4][NCB];
#pragma unroll
    for (int f = 0; f < 4; ++f)
#pragma unroll
        for (int n = 0; n < NCB; ++n) acc[f][n] = {0.f, 0.f, 0.f, 0.f};

    const _Float16* wqp = wqu + (size_t)(ph * 2 + pw) * KS * COUT * 32;

#pragma unroll
    for (int ko = 0; ko < KS; ++ko) {
        int tap = (ko * 32) / CIN;                  // constant after unroll
        int ci = (ko * 32) % CIN + grp * 8;
        int kd = tap >> 2, ih = (tap >> 1) & 1, iwk = tap & 1;

        int lcol = col + iwk + pw;                  // patch-local col
        int r0 = ih + ph;                           // patch-local row for f=0
        int cb = ((kd * IH + r0) * IW + lcol) * CIN + ci;
        half8 a[4];
#pragma unroll
        for (int f = 0; f < 4; ++f)
            a[f] = ldswz(lin, (cb + f * IW * CIN) * 2);

        half8 bfr[NCB];
#pragma unroll
        for (int n = 0; n < NCB; ++n)
            bfr[n] = *(const half8*)(wqp + ((ko * COUT + n * 16 + col) * 32 + grp * 8));
#pragma unroll
        for (int f = 0; f < 4; ++f)
#pragma unroll
            for (int n = 0; n < NCB; ++n)
                acc[f][n] = __builtin_amdgcn_mfma_f32_16x16x32_f16(a[f], bfr[n],
                                                                   acc[f][n], 0, 0, 0);
    }

    const size_t obase = (size_t)bz * S * S * COUT;
#pragma unroll
    for (int n = 0; n < NCB; ++n) {
        int co = n * 16 + col;
        float sh = bnsh[co];
#pragma unroll
        for (int f = 0; f < 4; ++f) {
            int h = 2 * (bhp + f) + ph;
#pragma unroll
            for (int r = 0; r < 4; ++r) {
                int w = 2 * (bwp + grp * 4 + r) + pw;
                float y = acc[f][n][r] + sh;
                float v = (n < NCB / 2) ? fast_tanh(y) : fast_sigmoid(y);
                gout[obase + ((size_t)h * S + w) * COUT + co] = (_Float16)v;
            }
        }
    }
}

// ---------------- fused qrnn scan (+skip add) ----------------
template <int H, int HW, int LAST>
__global__ __launch_bounds__(256) void qscan(
    const _Float16* __restrict__ g, const float* __restrict__ xs,
    _Float16* __restrict__ hout, float* __restrict__ fout, int rev) {
    constexpr int NCB = H / 8;
    int idx = blockIdx.x * 256 + threadIdx.x;
    if (idx >= BB * HW * NCB) return;
    int cb = idx % NCB;
    int hw = (idx / NCB) % HW;
    int b = idx / (NCB * HW);
    int c0 = cb * 8;

    float h[8];
#pragma unroll
    for (int j = 0; j < 8; ++j) h[j] = 0.f;

    for (int t = 0; t < DD; ++t) {
        int d = rev ? (DD - 1 - t) : t;
        const _Float16* gp = g + ((size_t)(b * DD + d) * HW + hw) * (2 * H);
        half8 z8 = *(const half8*)(gp + c0);
        half8 f8 = *(const half8*)(gp + H + c0);
        if (LAST) {
#pragma unroll
            for (int j = 0; j < 8; ++j) {
                float fv = (float)f8[j];
                h[j] = fv * h[j] + (1.f - fv) * (float)z8[j];
                fout[(((size_t)b * H + c0 + j) * DD + d) * HW + hw] = h[j];
            }
        } else {
            half8 o;
#pragma unroll
            for (int j = 0; j < 8; ++j) {
                float fv = (float)f8[j];
                h[j] = fv * h[j] + (1.f - fv) * (float)z8[j];
                o[j] = (_Float16)(h[j] + xs[(((size_t)b * H + c0 + j) * DD + d) * HW + hw]);
            }
            *(half8*)(hout + ((size_t)(b * DD + d) * HW + hw) * H + c0) = o;
        }
    }
}

extern "C" void kernel_launch(void* const* d_in, const int* in_sizes, int n_in,
                              void* d_out, int out_size, void* d_ws, size_t ws_size,
                              hipStream_t stream) {
    const float* x   = (const float*)d_in[0];
    const float* xs0 = (const float*)d_in[1];
    const float* xs1 = (const float*)d_in[2];
    const float* xs2 = (const float*)d_in[3];
    const float* w0  = (const float*)d_in[4];
    const float* w1  = (const float*)d_in[5];
    const float* w2  = (const float*)d_in[6];
    const float* w3  = (const float*)d_in[7];
    const float* bn0 = (const float*)d_in[8];
    const float* bn1 = (const float*)d_in[9];
    const float* bn2 = (const float*)d_in[10];
    const float* bn3 = (const float*)d_in[11];
    float* out = (float*)d_out;

    // ---- workspace layout ----
    char* p = (char*)d_ws;
    _Float16* xf = (_Float16*)p;  p += (size_t)124 * 1024 * 64 * 2;     // 16.25 MB
    _Float16* gA = (_Float16*)p;  p += (size_t)124 * 4096 * 64 * 2;     // 65 MB
    _Float16* hA = (_Float16*)p;  p += (size_t)124 * 4096 * 32 * 2;     // 32.5 MB
    _Float16* gB = (_Float16*)p;  p += (size_t)124 * 16384 * 32 * 2;    // 130 MB
    _Float16* hB = (_Float16*)p;  p += (size_t)124 * 16384 * 16 * 2;    // 65 MB
    _Float16* wqu0 = (_Float16*)p; p += (size_t)4 * 24 * 64 * 32 * 2;   // 384 KB
    _Float16* wq1  = (_Float16*)p; p += 27 * 64 * 32 * 2;
    _Float16* wqu2 = (_Float16*)p; p += (size_t)4 * 12 * 32 * 32 * 2;   // 96 KB
    _Float16* wq3  = (_Float16*)p; p += 14 * 32 * 32 * 2;
    float* sh0 = (float*)p;       p += 64 * 4;
    float* sh1 = (float*)p;       p += 64 * 4;
    float* sh2 = (float*)p;       p += 64 * 4;
    float* sh3 = (float*)p;       p += 64 * 4;

    // ---- prep ----
    xconv<<<(4 * 31 * 1024 * 8 + 255) / 256, 256, 0, stream>>>(x, xf);
    wprep_up<<<(4 * 24 * 32 * 64 + 255) / 256, 256, 0, stream>>>(w0, bn0, wqu0, 64, 64);
    wprep<<<(27 * 32 * 64 + 255) / 256, 256, 0, stream>>>(w1, bn1, wq1, 32, 64, 27, 1);
    wprep_up<<<(4 * 12 * 32 * 32 + 255) / 256, 256, 0, stream>>>(w2, bn2, wqu2, 32, 32);
    wprep<<<(14 * 32 * 32 + 255) / 256, 256, 0, stream>>>(w3, bn3, wq3, 16, 32, 14, 1);
    bnprep<<<1, 64, 0, stream>>>(bn0, 64, sh0);
    bnprep<<<1, 64, 0, stream>>>(bn1, 64, sh1);
    bnprep<<<1, 64, 0, stream>>>(bn2, 32, sh2);
    bnprep<<<1, 64, 0, stream>>>(bn3, 32, sh3);

    // ---- layer 1: up(x) -> conv w0 (64->64) @64, fwd; h1 += xs2 ----
    conv_up<64, 64, 64, 3><<<dim3(2, 8, BB * DD), 256, 0, stream>>>(xf, wqu0, sh0, gA);
    qscan<32, 4096, 0><<<(BB * 4096 * 4 + 255) / 256, 256, 0, stream>>>(gA, xs2, hA, nullptr, 0);

    // ---- layer 2: deconv w1 (32->64) @64, rev; h2 += xs1 ----
    conv_mfma<32, 64, 64, 27><<<dim3(4, 4, BB * DD), 256, 0, stream>>>(hA, wq1, sh1, gA);
    qscan<32, 4096, 0><<<(BB * 4096 * 4 + 255) / 256, 256, 0, stream>>>(gA, xs1, hA, nullptr, 1);

    // ---- layer 3: up -> conv w2 (32->32) @128, fwd; h3 += xs0 ----
    conv_up<32, 32, 128, 4><<<dim3(4, 16, BB * DD), 256, 0, stream>>>(hA, wqu2, sh2, gB);
    qscan<16, 16384, 0><<<(BB * 16384 * 2 + 255) / 256, 256, 0, stream>>>(gB, xs0, hB, nullptr, 0);

    // ---- layer 4: deconv w3 (16->32) @128, rev; out fp32 ----
    conv_mfma<16, 32, 128, 14><<<dim3(8, 8, BB * DD), 256, 0, stream>>>(hB, wq3, sh3, gB);
    qscan<16, 16384, 1><<<(BB * 16384 * 2 + 255) / 256, 256, 0, stream>>>(gB, nullptr, nullptr, out, 1);
}